// Round 4
// baseline (429.499 us; speedup 1.0000x reference)
//
#include <hip/hip_runtime.h>
#include <math.h>

#define NS 64
#define INV2PI  0.15915494309189535f
#define NEGHL2E (-0.72134752044448170f)   // -0.5 * log2(e)

typedef __attribute__((ext_vector_type(4))) float vfloat4;  // native clang vector (nontemporal-store OK)

// P (3x21) flat row-major, exactly as in the reference.
__constant__ float c_P[63] = {
  0.8506508f, 0.0f, 0.5257311f, 0.809017f, 0.5f, 0.309017f, 0.5257311f,
  0.8506508f, 0.0f, 1.0f, 0.0f, 0.0f, 0.809017f, 0.5f, -0.309017f,
  0.8506508f, 0.0f, -0.5257311f, 0.309017f, 0.809017f, -0.5f,
  0.0f, 0.5257311f, -0.8506508f, 0.5f, 0.309017f, -0.809017f, 0.0f, 1.0f,
  0.0f, -0.5257311f, 0.8506508f, 0.0f, -0.309017f, 0.809017f, -0.5f, 0.0f,
  0.5257311f, 0.8506508f, -0.309017f, 0.809017f, 0.5f,
  0.309017f, 0.809017f, 0.5f, 0.5f, 0.309017f, 0.809017f, 0.5f, -0.309017f,
  0.809017f, 0.0f, 0.0f, 1.0f, -0.5f, 0.309017f, 0.809017f, -0.809017f,
  0.5f, 0.309017f, -0.809017f, 0.5f, -0.309017f
};

// Per-pair descriptor: ((127+deg)<<23) | (src*8). 384 pairs, compile-time.
struct DescTab { unsigned v[384]; };
static constexpr DescTab make_desc() {
    DescTab t{};
    for (int e = 0; e < 384; ++e) {
        int deg, src;
        if (e < 48) { deg = e / 3;  src = 21 + (e - 3 * deg); }
        else        { int jj = e - 48; deg = jj / 21; src = jj - 21 * deg; }
        t.v[e] = ((unsigned)(127 + deg) << 23) | ((unsigned)src << 3);
    }
    return t;
}
__constant__ DescTab cDesc = make_desc();

struct Moments { float t_mean, t_var, r_var; };

__device__ inline Moments frustum_moments(float t0, float t1, float radius) {
    float mu  = 0.5f * (t0 + t1);
    float hw  = 0.5f * (t1 - t0);
    float mu2 = mu * mu, hw2 = hw * hw;
    float denom = 3.0f * mu2 + hw2;
    float inv_d = 1.0f / denom;
    float hw4 = hw2 * hw2;
    Moments m;
    m.t_mean = mu + 2.0f * mu * hw2 * inv_d;
    m.t_var  = hw2 * (1.0f / 3.0f)
             - (4.0f / 15.0f) * (hw4 * (12.0f * mu2 - hw2) * inv_d * inv_d);
    m.r_var  = radius * radius *
               (0.25f * mu2 + (5.0f / 12.0f) * hw2 - (4.0f / 15.0f) * hw4 * inv_d);
    return m;
}

// ============================================================================
// Kernel A: per (ray, sample) compute all 24 (X, V) pairs into ws.
// Row layout: ws[(ray*64+s)*24 + src] = float2(X, V); bg srcs 0..20, fg 21..23.
// Bit-identical math to the verified single-kernel version.
// ============================================================================
__global__ __launch_bounds__(256) void mipnerf_prep(
    const float* __restrict__ ray_o,
    const float* __restrict__ ray_d,
    const float* __restrict__ fgz,
    const float* __restrict__ bgz,
    const float* __restrict__ radii,
    float2* __restrict__ ws)
{
    const int idx = blockIdx.x * 256 + threadIdx.x;
    const int n = idx >> 6;        // ray
    const int s = idx & (NS - 1);  // sample

    const float ox = ray_o[3 * n + 0], oy = ray_o[3 * n + 1], oz = ray_o[3 * n + 2];
    const float dx = ray_d[3 * n + 0], dy = ray_d[3 * n + 1], dz = ray_d[3 * n + 2];
    const float rad = radii[n];
    const float dm = fmaxf(1e-8f, dx * dx + dy * dy + dz * dz);
    const float inv_dm = 1.0f / dm;

    float2* __restrict__ row = ws + (size_t)idx * 24;

    { // ---- FG (diagonal covariance) ----
        float t0 = fgz[(NS + 1) * n + s];
        float t1 = fgz[(NS + 1) * n + s + 1];
        Moments mm = frustum_moments(t0, t1, rad);
        float d3[3] = {dx, dy, dz};
        float o3[3] = {ox, oy, oz};
        #pragma unroll
        for (int i = 0; i < 3; ++i) {
            float m  = o3[i] + d3[i] * mm.t_mean;
            float dd = d3[i] * d3[i];
            float cd = mm.t_var * dd + mm.r_var * (1.0f - dd * inv_dm);
            row[21 + i] = make_float2(m * INV2PI, cd * NEGHL2E);
        }
    }
    { // ---- BG core (full cov + contraction) + 21 projections ----
        float t0 = bgz[(NS + 1) * n + s];
        float t1 = bgz[(NS + 1) * n + s + 1];
        Moments mm = frustum_moments(t0, t1, rad);
        float x0 = ox + dx * mm.t_mean;
        float x1 = oy + dy * mm.t_mean;
        float x2 = oz + dz * mm.t_mean;
        float a  = mm.t_var - mm.r_var * inv_dm;   // C = a*ddT + rv*I
        float rv = mm.r_var;
        float rn2 = x0 * x0 + x1 * x1 + x2 * x2;
        float rn  = sqrtf(rn2);
        float nn  = rn + 1e-6f;
        float inn = 1.0f / nn;
        float g   = (2.0f * nn - 1.0f) * inn * inn;       // (2 - 1/n)/n
        float gp  = 2.0f * (1.0f - nn) * inn * inn * inn; // g'(n)
        float h   = gp / rn;                              // J = g*I + h*x*xT
        float xd  = x0 * dx + x1 * dy + x2 * dz;
        float hxd = h * xd;
        float u0 = g * dx + hxd * x0;                     // u = J d
        float u1 = g * dy + hxd * x1;
        float u2 = g * dz + hxd * x2;
        float w  = 2.0f * g * h + h * h * rn2;            // J^2 = g^2 I + w x xT
        float c1 = a, c2 = rv * g * g, c3 = rv * w;
        #pragma unroll
        for (int k = 0; k < 21; ++k) {
            const float p0 = c_P[k], p1 = c_P[21 + k], p2 = c_P[42 + k];
            float dpx = p0 * x0 + p1 * x1 + p2 * x2;
            float dpu = p0 * u0 + p1 * u1 + p2 * u2;
            float pp  = p0 * p0 + p1 * p1 + p2 * p2;
            float y   = g * dpx;
            float yv  = c1 * dpu * dpu + c2 * pp + c3 * dpx * dpx;
            row[k] = make_float2(y * INV2PI, yv * NEGHL2E);
        }
    }
}

// ============================================================================
// Kernel B: pure streaming emit. No LDS, no barriers. One ray per block.
// Per pair-slot: 1 uint4 constant read + 4 float2 L1-hot reads
// -> 2 nontemporal float4 stores. Store addresses identical to round 3.
// ============================================================================
__global__ __launch_bounds__(256, 4) void mipnerf_emit(
    const float2* __restrict__ ws,
    float* __restrict__ out)
{
    const int n   = blockIdx.x;
    const int tid = threadIdx.x;
    const char* __restrict__ wbase = reinterpret_cast<const char*>(ws + (size_t)n * (NS * 24));
    float* __restrict__ outp = out + (size_t)n * (NS * 768);
    const unsigned* dtab = cDesc.v;

    for (int it = 0; it < 24; ++it) {
        int p  = it * 256 + tid;       // pair-slot id in [0, 6144)
        int s  = p / 96;               // sample
        int j0 = (p - s * 96) << 2;    // first pair index (multiple of 4)
        const uint4 w4 = *reinterpret_cast<const uint4*>(&dtab[j0]);
        const char* rowXV = wbase + s * 192;   // 24 float2 = 192 B per sample
        const bool fg = (j0 < 48);

        vfloat4 vs, vc;
        {
            unsigned w = w4.x;
            float sf = __uint_as_float(w & 0xFF800000u);            // 2^deg
            float2 xv = *reinterpret_cast<const float2*>(rowXV + (w & 0xFFu));
            float e  = __builtin_amdgcn_exp2f(xv.y * (sf * sf));    // exp(-0.5*var*4^deg)
            float xs = xv.x * sf;
            vs.x = e * __builtin_amdgcn_sinf(__builtin_amdgcn_fractf(xs));
            vc.x = e * __builtin_amdgcn_sinf(__builtin_amdgcn_fractf(xs + 0.25f));
        }
        {
            unsigned w = w4.y;
            float sf = __uint_as_float(w & 0xFF800000u);
            float2 xv = *reinterpret_cast<const float2*>(rowXV + (w & 0xFFu));
            float e  = __builtin_amdgcn_exp2f(xv.y * (sf * sf));
            float xs = xv.x * sf;
            vs.y = e * __builtin_amdgcn_sinf(__builtin_amdgcn_fractf(xs));
            vc.y = e * __builtin_amdgcn_sinf(__builtin_amdgcn_fractf(xs + 0.25f));
        }
        {
            unsigned w = w4.z;
            float sf = __uint_as_float(w & 0xFF800000u);
            float2 xv = *reinterpret_cast<const float2*>(rowXV + (w & 0xFFu));
            float e  = __builtin_amdgcn_exp2f(xv.y * (sf * sf));
            float xs = xv.x * sf;
            vs.z = e * __builtin_amdgcn_sinf(__builtin_amdgcn_fractf(xs));
            vc.z = e * __builtin_amdgcn_sinf(__builtin_amdgcn_fractf(xs + 0.25f));
        }
        {
            unsigned w = w4.w;
            float sf = __uint_as_float(w & 0xFF800000u);
            float2 xv = *reinterpret_cast<const float2*>(rowXV + (w & 0xFFu));
            float e  = __builtin_amdgcn_exp2f(xv.y * (sf * sf));
            float xs = xv.x * sf;
            vs.w = e * __builtin_amdgcn_sinf(__builtin_amdgcn_fractf(xs));
            vc.w = e * __builtin_amdgcn_sinf(__builtin_amdgcn_fractf(xs + 0.25f));
        }

        float* o1 = outp + (s * 768 + (fg ? j0 : j0 + 48));
        float* o2 = o1 + (fg ? 48 : 336);
        __builtin_nontemporal_store(vs, reinterpret_cast<vfloat4*>(o1));
        __builtin_nontemporal_store(vc, reinterpret_cast<vfloat4*>(o2));
    }
}

// ============================================================================
// Fallback: the round-3 harness-verified single kernel (unchanged).
// ============================================================================
__global__ __launch_bounds__(256, 4) void mipnerf_enc(
    const float* __restrict__ ray_o,
    const float* __restrict__ ray_d,
    const float* __restrict__ fgz,
    const float* __restrict__ bgz,
    const float* __restrict__ radii,
    float* __restrict__ out)
{
    const int n   = blockIdx.x;
    const int tid = threadIdx.x;

    __shared__ float sXV[NS * 50];
    __shared__ float sCore[NS * 11];
    __shared__ unsigned int sDesc[384];

    const float ox = ray_o[3 * n + 0], oy = ray_o[3 * n + 1], oz = ray_o[3 * n + 2];
    const float dx = ray_d[3 * n + 0], dy = ray_d[3 * n + 1], dz = ray_d[3 * n + 2];
    const float rad = radii[n];
    const float dm = fmaxf(1e-8f, dx * dx + dy * dy + dz * dz);
    const float inv_dm = 1.0f / dm;

    if (tid < NS) {
        const int s = tid;
        {
            float t0 = fgz[(NS + 1) * n + s];
            float t1 = fgz[(NS + 1) * n + s + 1];
            Moments mm = frustum_moments(t0, t1, rad);
            float d3[3] = {dx, dy, dz};
            float o3[3] = {ox, oy, oz};
            #pragma unroll
            for (int i = 0; i < 3; ++i) {
                float m  = o3[i] + d3[i] * mm.t_mean;
                float dd = d3[i] * d3[i];
                float cd = mm.t_var * dd + mm.r_var * (1.0f - dd * inv_dm);
                sXV[s * 50 + 2 * (21 + i) + 0] = m  * INV2PI;
                sXV[s * 50 + 2 * (21 + i) + 1] = cd * NEGHL2E;
            }
        }
        {
            float t0 = bgz[(NS + 1) * n + s];
            float t1 = bgz[(NS + 1) * n + s + 1];
            Moments mm = frustum_moments(t0, t1, rad);
            float x0 = ox + dx * mm.t_mean;
            float x1 = oy + dy * mm.t_mean;
            float x2 = oz + dz * mm.t_mean;
            float a  = mm.t_var - mm.r_var * inv_dm;
            float rv = mm.r_var;
            float rn2 = x0 * x0 + x1 * x1 + x2 * x2;
            float rn  = sqrtf(rn2);
            float nn  = rn + 1e-6f;
            float inn = 1.0f / nn;
            float g   = (2.0f * nn - 1.0f) * inn * inn;
            float gp  = 2.0f * (1.0f - nn) * inn * inn * inn;
            float h   = gp / rn;
            float xd  = x0 * dx + x1 * dy + x2 * dz;
            float hxd = h * xd;
            float u0 = g * dx + hxd * x0;
            float u1 = g * dy + hxd * x1;
            float u2 = g * dz + hxd * x2;
            float w  = 2.0f * g * h + h * h * rn2;
            float* cr = &sCore[s * 11];
            cr[0] = x0; cr[1] = x1; cr[2] = x2;
            cr[3] = u0; cr[4] = u1; cr[5] = u2;
            cr[6] = g;  cr[7] = a;  cr[8] = rv * g * g; cr[9] = rv * w;
        }
    } else {
        for (int e = tid - NS; e < 384; e += 256 - NS) {
            int deg, src;
            if (e < 48) { deg = e / 3;  src = 21 + (e - 3 * deg); }
            else { int jj = e - 48; deg = jj / 21; src = jj - 21 * deg; }
            sDesc[e] = ((unsigned)(127 + deg) << 23) | ((unsigned)src << 3);
        }
    }
    __syncthreads();

    #pragma unroll
    for (int j = 0; j < 6; ++j) {
        int i = tid + 256 * j;
        if (i < 21 * NS) {
            int k = i >> 6;
            int s = i & (NS - 1);
            const float p0 = c_P[k], p1 = c_P[21 + k], p2 = c_P[42 + k];
            const float* cr = &sCore[s * 11];
            float x0 = cr[0], x1 = cr[1], x2 = cr[2];
            float u0 = cr[3], u1 = cr[4], u2 = cr[5];
            float g = cr[6], c1 = cr[7], c2 = cr[8], c3 = cr[9];
            float dpx = p0 * x0 + p1 * x1 + p2 * x2;
            float dpu = p0 * u0 + p1 * u1 + p2 * u2;
            float pp  = p0 * p0 + p1 * p1 + p2 * p2;
            float y   = g * dpx;
            float yv  = c1 * dpu * dpu + c2 * pp + c3 * dpx * dpx;
            sXV[s * 50 + 2 * k + 0] = y  * INV2PI;
            sXV[s * 50 + 2 * k + 1] = yv * NEGHL2E;
        }
    }
    __syncthreads();

    float* __restrict__ outp = out + (size_t)n * (NS * 768);

    for (int it = 0; it < 24; ++it) {
        int p  = tid + 256 * it;
        int s  = p / 96;
        int j0 = (p - s * 96) << 2;
        const uint4 w4 = *reinterpret_cast<const uint4*>(&sDesc[j0]);
        const char* rowXV = reinterpret_cast<const char*>(&sXV[s * 50]);
        const bool fg = (j0 < 48);

        vfloat4 vs, vc;
        {
            unsigned w = w4.x;
            float sf = __uint_as_float(w & 0xFF800000u);
            float2 xv = *reinterpret_cast<const float2*>(rowXV + (w & 0xFFu));
            float e  = __builtin_amdgcn_exp2f(xv.y * (sf * sf));
            float xs = xv.x * sf;
            vs.x = e * __builtin_amdgcn_sinf(__builtin_amdgcn_fractf(xs));
            vc.x = e * __builtin_amdgcn_sinf(__builtin_amdgcn_fractf(xs + 0.25f));
        }
        {
            unsigned w = w4.y;
            float sf = __uint_as_float(w & 0xFF800000u);
            float2 xv = *reinterpret_cast<const float2*>(rowXV + (w & 0xFFu));
            float e  = __builtin_amdgcn_exp2f(xv.y * (sf * sf));
            float xs = xv.x * sf;
            vs.y = e * __builtin_amdgcn_sinf(__builtin_amdgcn_fractf(xs));
            vc.y = e * __builtin_amdgcn_sinf(__builtin_amdgcn_fractf(xs + 0.25f));
        }
        {
            unsigned w = w4.z;
            float sf = __uint_as_float(w & 0xFF800000u);
            float2 xv = *reinterpret_cast<const float2*>(rowXV + (w & 0xFFu));
            float e  = __builtin_amdgcn_exp2f(xv.y * (sf * sf));
            float xs = xv.x * sf;
            vs.z = e * __builtin_amdgcn_sinf(__builtin_amdgcn_fractf(xs));
            vc.z = e * __builtin_amdgcn_sinf(__builtin_amdgcn_fractf(xs + 0.25f));
        }
        {
            unsigned w = w4.w;
            float sf = __uint_as_float(w & 0xFF800000u);
            float2 xv = *reinterpret_cast<const float2*>(rowXV + (w & 0xFFu));
            float e  = __builtin_amdgcn_exp2f(xv.y * (sf * sf));
            float xs = xv.x * sf;
            vs.w = e * __builtin_amdgcn_sinf(__builtin_amdgcn_fractf(xs));
            vc.w = e * __builtin_amdgcn_sinf(__builtin_amdgcn_fractf(xs + 0.25f));
        }

        float* o1 = outp + (s * 768 + (fg ? j0 : j0 + 48));
        float* o2 = o1 + (fg ? 48 : 336);
        __builtin_nontemporal_store(vs, reinterpret_cast<vfloat4*>(o1));
        __builtin_nontemporal_store(vc, reinterpret_cast<vfloat4*>(o2));
    }
}

extern "C" void kernel_launch(void* const* d_in, const int* in_sizes, int n_in,
                              void* d_out, int out_size, void* d_ws, size_t ws_size,
                              hipStream_t stream) {
    const float* ray_o = (const float*)d_in[0];
    const float* ray_d = (const float*)d_in[1];
    const float* fgz   = (const float*)d_in[2];
    const float* bgz   = (const float*)d_in[3];
    const float* radii = (const float*)d_in[4];
    float* out = (float*)d_out;
    const int N = in_sizes[0] / 3;   // 2048 rays

    const size_t need = (size_t)N * NS * 24 * sizeof(float2);  // 25.2 MB for N=2048
    if (d_ws != nullptr && ws_size >= need && (N % 4) == 0) {
        mipnerf_prep<<<(N * NS) / 256, 256, 0, stream>>>(ray_o, ray_d, fgz, bgz, radii,
                                                         (float2*)d_ws);
        mipnerf_emit<<<N, 256, 0, stream>>>((const float2*)d_ws, out);
    } else {
        mipnerf_enc<<<N, 256, 0, stream>>>(ray_o, ray_d, fgz, bgz, radii, out);
    }
}

// Round 5
// 406.693 us; speedup vs baseline: 1.0561x; 1.0561x over previous
//
#include <hip/hip_runtime.h>
#include <math.h>

#define NS 64
#define INV2PI  0.15915494309189535f
#define NEGHL2E (-0.72134752044448170f)   // -0.5 * log2(e)

typedef __attribute__((ext_vector_type(4))) float vfloat4;  // native clang vector (nontemporal-store OK)

// P (3x21) flat row-major, exactly as in the reference.
__constant__ float c_P[63] = {
  0.8506508f, 0.0f, 0.5257311f, 0.809017f, 0.5f, 0.309017f, 0.5257311f,
  0.8506508f, 0.0f, 1.0f, 0.0f, 0.0f, 0.809017f, 0.5f, -0.309017f,
  0.8506508f, 0.0f, -0.5257311f, 0.309017f, 0.809017f, -0.5f,
  0.0f, 0.5257311f, -0.8506508f, 0.5f, 0.309017f, -0.809017f, 0.0f, 1.0f,
  0.0f, -0.5257311f, 0.8506508f, 0.0f, -0.309017f, 0.809017f, -0.5f, 0.0f,
  0.5257311f, 0.8506508f, -0.309017f, 0.809017f, 0.5f,
  0.309017f, 0.809017f, 0.5f, 0.5f, 0.309017f, 0.809017f, 0.5f, -0.309017f,
  0.809017f, 0.0f, 0.0f, 1.0f, -0.5f, 0.309017f, 0.809017f, -0.809017f,
  0.5f, 0.309017f, -0.809017f, 0.5f, -0.309017f
};

// Per-CHANNEL descriptor (768 entries): ((127+deg)<<23) | (src<<3) | phase.
// Channel map (matches reference concat layout, verified rounds 0/3):
//   c in [0,48)    : fg sin, deg=c/3,        src=21+c%3, ph=0
//   c in [48,96)   : fg cos, cc=c-48,  deg=cc/3,  src=21+cc%3, ph=1
//   c in [96,432)  : bg sin, cc=c-96,  deg=cc/21, src=cc%21,   ph=0
//   c in [432,768) : bg cos, cc=c-432, deg=cc/21, src=cc%21,   ph=1
struct DescTab768 { unsigned v[768]; };
static constexpr DescTab768 make_desc768() {
    DescTab768 t{};
    for (int c = 0; c < 768; ++c) {
        int deg, src, ph;
        if      (c < 48)  { deg = c / 3;               src = 21 + c % 3;        ph = 0; }
        else if (c < 96)  { int cc = c - 48;  deg = cc / 3;  src = 21 + cc % 3; ph = 1; }
        else if (c < 432) { int cc = c - 96;  deg = cc / 21; src = cc % 21;     ph = 0; }
        else              { int cc = c - 432; deg = cc / 21; src = cc % 21;     ph = 1; }
        t.v[c] = ((unsigned)(127 + deg) << 23) | ((unsigned)src << 3) | (unsigned)ph;
    }
    return t;
}
__constant__ DescTab768 cDesc = make_desc768();

struct Moments { float t_mean, t_var, r_var; };

__device__ inline Moments frustum_moments(float t0, float t1, float radius) {
    float mu  = 0.5f * (t0 + t1);
    float hw  = 0.5f * (t1 - t0);
    float mu2 = mu * mu, hw2 = hw * hw;
    float denom = 3.0f * mu2 + hw2;
    float inv_d = 1.0f / denom;
    float hw4 = hw2 * hw2;
    Moments m;
    m.t_mean = mu + 2.0f * mu * hw2 * inv_d;
    m.t_var  = hw2 * (1.0f / 3.0f)
             - (4.0f / 15.0f) * (hw4 * (12.0f * mu2 - hw2) * inv_d * inv_d);
    m.r_var  = radius * radius *
               (0.25f * mu2 + (5.0f / 12.0f) * hw2 - (4.0f / 15.0f) * hw4 * inv_d);
    return m;
}

// Emit 4 consecutive channels (one float4) from a per-lane descriptor quad.
__device__ inline void emit4(uint4 d, const char* __restrict__ rowXV, float* __restrict__ o) {
    vfloat4 v;
    {
        unsigned wd = d.x;
        float sf = __uint_as_float(wd & 0xFF800000u);                 // 2^deg
        float2 xv = *reinterpret_cast<const float2*>(rowXV + (wd & 0xF8u));
        float e  = __builtin_amdgcn_exp2f(xv.y * (sf * sf));          // exp(-0.5*var*4^deg)
        float ph = (float)(wd & 1u) * 0.25f;
        v.x = e * __builtin_amdgcn_sinf(__builtin_amdgcn_fractf(xv.x * sf + ph));
    }
    {
        unsigned wd = d.y;
        float sf = __uint_as_float(wd & 0xFF800000u);
        float2 xv = *reinterpret_cast<const float2*>(rowXV + (wd & 0xF8u));
        float e  = __builtin_amdgcn_exp2f(xv.y * (sf * sf));
        float ph = (float)(wd & 1u) * 0.25f;
        v.y = e * __builtin_amdgcn_sinf(__builtin_amdgcn_fractf(xv.x * sf + ph));
    }
    {
        unsigned wd = d.z;
        float sf = __uint_as_float(wd & 0xFF800000u);
        float2 xv = *reinterpret_cast<const float2*>(rowXV + (wd & 0xF8u));
        float e  = __builtin_amdgcn_exp2f(xv.y * (sf * sf));
        float ph = (float)(wd & 1u) * 0.25f;
        v.z = e * __builtin_amdgcn_sinf(__builtin_amdgcn_fractf(xv.x * sf + ph));
    }
    {
        unsigned wd = d.w;
        float sf = __uint_as_float(wd & 0xFF800000u);
        float2 xv = *reinterpret_cast<const float2*>(rowXV + (wd & 0xF8u));
        float e  = __builtin_amdgcn_exp2f(xv.y * (sf * sf));
        float ph = (float)(wd & 1u) * 0.25f;
        v.w = e * __builtin_amdgcn_sinf(__builtin_amdgcn_fractf(xv.x * sf + ph));
    }
    __builtin_nontemporal_store(v, reinterpret_cast<vfloat4*>(o));
}

__global__ __launch_bounds__(256, 4) void mipnerf_enc(
    const float* __restrict__ ray_o,
    const float* __restrict__ ray_d,
    const float* __restrict__ fgz,
    const float* __restrict__ bgz,
    const float* __restrict__ radii,
    float* __restrict__ out)
{
    const int n   = blockIdx.x;
    const int tid = threadIdx.x;

    // Per-sample sources: 24 pairs (X = x/2pi, V = -0.5*log2e * var), stride 50 floats (odd/2 pad).
    __shared__ float sXV[NS * 50];
    // Per-sample bg core: x0..2, u0..2, g, c1, c2, c3 (stride 11).
    __shared__ float sCore[NS * 11];
    // Per-channel descriptors, copied from __constant__ (16B-aligned for uint4 reads).
    __shared__ __align__(16) unsigned sD[768];

    const float ox = ray_o[3 * n + 0], oy = ray_o[3 * n + 1], oz = ray_o[3 * n + 2];
    const float dx = ray_d[3 * n + 0], dy = ray_d[3 * n + 1], dz = ray_d[3 * n + 2];
    const float rad = radii[n];
    const float dm = fmaxf(1e-8f, dx * dx + dy * dy + dz * dz);
    const float inv_dm = 1.0f / dm;

    if (tid < NS) {
        const int s = tid;
        { // ---- FG (diagonal covariance) ----
            float t0 = fgz[(NS + 1) * n + s];
            float t1 = fgz[(NS + 1) * n + s + 1];
            Moments mm = frustum_moments(t0, t1, rad);
            float d3[3] = {dx, dy, dz};
            float o3[3] = {ox, oy, oz};
            #pragma unroll
            for (int i = 0; i < 3; ++i) {
                float m  = o3[i] + d3[i] * mm.t_mean;
                float dd = d3[i] * d3[i];
                float cd = mm.t_var * dd + mm.r_var * (1.0f - dd * inv_dm);
                sXV[s * 50 + 2 * (21 + i) + 0] = m  * INV2PI;
                sXV[s * 50 + 2 * (21 + i) + 1] = cd * NEGHL2E;
            }
        }
        { // ---- BG core (full cov + contraction, closed form) ----
            float t0 = bgz[(NS + 1) * n + s];
            float t1 = bgz[(NS + 1) * n + s + 1];
            Moments mm = frustum_moments(t0, t1, rad);
            float x0 = ox + dx * mm.t_mean;
            float x1 = oy + dy * mm.t_mean;
            float x2 = oz + dz * mm.t_mean;
            float a  = mm.t_var - mm.r_var * inv_dm;   // C = a*ddT + rv*I
            float rv = mm.r_var;
            float rn2 = x0 * x0 + x1 * x1 + x2 * x2;
            float rn  = sqrtf(rn2);
            float nn  = rn + 1e-6f;
            float inn = 1.0f / nn;
            float g   = (2.0f * nn - 1.0f) * inn * inn;       // (2 - 1/n)/n
            float gp  = 2.0f * (1.0f - nn) * inn * inn * inn; // g'(n)
            float h   = gp / rn;                              // J = g*I + h*x*xT
            float xd  = x0 * dx + x1 * dy + x2 * dz;
            float hxd = h * xd;
            float u0 = g * dx + hxd * x0;                     // u = J d
            float u1 = g * dy + hxd * x1;
            float u2 = g * dz + hxd * x2;
            float w  = 2.0f * g * h + h * h * rn2;            // J^2 = g^2 I + w x xT
            float* cr = &sCore[s * 11];
            cr[0] = x0; cr[1] = x1; cr[2] = x2;
            cr[3] = u0; cr[4] = u1; cr[5] = u2;
            cr[6] = g;  cr[7] = a;  cr[8] = rv * g * g; cr[9] = rv * w;
        }
    } else {
        // ---- Copy channel descriptors to LDS (these 192 threads were idle) ----
        for (int e = tid - NS; e < 768; e += 256 - NS) sD[e] = cDesc.v[e];
    }
    __syncthreads();

    // ---- BG projections onto 21 basis columns (k wave-uniform, s = lane) ----
    #pragma unroll
    for (int j = 0; j < 6; ++j) {
        int i = tid + 256 * j;
        if (i < 21 * NS) {
            int k = i >> 6;        // wave-uniform
            int s = i & (NS - 1);  // = lane
            const float p0 = c_P[k], p1 = c_P[21 + k], p2 = c_P[42 + k];
            const float* cr = &sCore[s * 11];
            float x0 = cr[0], x1 = cr[1], x2 = cr[2];
            float u0 = cr[3], u1 = cr[4], u2 = cr[5];
            float g = cr[6], c1 = cr[7], c2 = cr[8], c3 = cr[9];
            float dpx = p0 * x0 + p1 * x1 + p2 * x2;
            float dpu = p0 * u0 + p1 * u1 + p2 * u2;
            float pp  = p0 * p0 + p1 * p1 + p2 * p2;
            float y   = g * dpx;
            float yv  = c1 * dpu * dpu + c2 * pp + c3 * dpx * dpx;
            sXV[s * 50 + 2 * k + 0] = y  * INV2PI;
            sXV[s * 50 + 2 * k + 1] = yv * NEGHL2E;
        }
    }
    __syncthreads();

    // ---- Emit: strictly-linear per-wave store stream (H1 probe). ----
    // Wave w owns samples [16w, 16w+16) = one contiguous 48 KB run.
    // Per sample row (3072 B): 3 ascending 1 KB coalesced NT stores.
    // Descriptors hoisted to registers; inner loop has zero vmcnt waits.
    const int lane = tid & 63;
    const int w    = tid >> 6;     // wave id 0..3
    const uint4* sD4 = reinterpret_cast<const uint4*>(sD);
    const uint4 d0 = sD4[lane];        // channels   0 + lane*4 .. +3
    const uint4 d1 = sD4[64 + lane];   // channels 256 + lane*4 .. +3
    const uint4 d2 = sD4[128 + lane];  // channels 512 + lane*4 .. +3

    float* __restrict__ outp = out + (size_t)n * (NS * 768);

    for (int ss = 0; ss < 16; ++ss) {
        const int s = w * 16 + ss;
        const char* rowXV = reinterpret_cast<const char*>(&sXV[s * 50]);
        float* orow = outp + s * 768 + lane * 4;
        emit4(d0, rowXV, orow);
        emit4(d1, rowXV, orow + 256);
        emit4(d2, rowXV, orow + 512);
    }
}

extern "C" void kernel_launch(void* const* d_in, const int* in_sizes, int n_in,
                              void* d_out, int out_size, void* d_ws, size_t ws_size,
                              hipStream_t stream) {
    const float* ray_o = (const float*)d_in[0];
    const float* ray_d = (const float*)d_in[1];
    const float* fgz   = (const float*)d_in[2];
    const float* bgz   = (const float*)d_in[3];
    const float* radii = (const float*)d_in[4];
    float* out = (float*)d_out;
    const int N = in_sizes[0] / 3;   // 2048 rays
    mipnerf_enc<<<N, 256, 0, stream>>>(ray_o, ray_d, fgz, bgz, radii, out);
}